// Round 2
// baseline (112.090 us; speedup 1.0000x reference)
//
#include <hip/hip_runtime.h>

// Problem constants (fixed by setup_inputs): seg (1,1,2160,3840) int32, S=512.
#define HH 2160
#define WW 3840
#define SS 512
#define NWORDS (SS * SS / 32)   // 8192 u32 words in the adjacency bitmask

typedef unsigned int uint;
typedef unsigned long long ull;

// ---------------------------------------------------------------------------
// Main pass: one sweep over the image.
//  - adjacency: set bit (s*512+n) in a per-block LDS bitmask for each
//    right/down neighbor n != s; flush via global atomicOr into wsOr.
//  - centers:   per-block LDS histogram, packed (cnt<<40 | sum_y) u64 atomic
//    + sum_x u32 atomic; flush per-block partials to part.
// part layout: uint part[3][SS][nb]  (plane 0=cnt, 1=sum_x, 2=sum_y)
// Overflow check (per block, worst case all 16200 pixels in one segment):
//   cnt <= 16200 < 2^24;  sy <= 16200*2159 ~ 3.5e7 < 2^40;  sx <= 6.3e7 < 2^32.
// ---------------------------------------------------------------------------
__global__ __launch_bounds__(512) void seg_main(
    const int* __restrict__ seg, uint* __restrict__ wsOr,
    uint* __restrict__ part, int nb) {
  __shared__ uint s_bm[NWORDS];  // 32 KB adjacency bitmask
  __shared__ ull  s_pk[SS];      // (cnt << 40) | sum_y
  __shared__ uint s_sx[SS];      // sum_x
  for (int i = threadIdx.x; i < NWORDS; i += blockDim.x) s_bm[i] = 0u;
  for (int i = threadIdx.x; i < SS; i += blockDim.x) { s_pk[i] = 0ULL; s_sx[i] = 0u; }
  __syncthreads();

  const int NC = HH * WW / 4;  // int4 chunks; WW % 4 == 0 so chunks never span rows
  const int stride = gridDim.x * blockDim.x;
  const int4* __restrict__ seg4  = (const int4*)seg;
  const int4* __restrict__ seg4d = (const int4*)(seg + WW);  // same chunk idx -> next row

  for (int c = blockIdx.x * blockDim.x + threadIdx.x; c < NC; c += stride) {
    const int p = c * 4;
    const int y = p / WW;
    const int x = p - y * WW;
    const int4 v = seg4[c];
    // down neighbors (clamped at last row -> self -> no edge)
    const int4 d = (y < HH - 1) ? seg4d[c] : v;
    // right neighbor of element 3 (clamped at last column -> self -> no edge)
    const int nxt = (x < WW - 4) ? seg[p + 4] : v.w;

    // adjacency bits: pair (s -> right(s)) and (s -> down(s)), s != n only,
    // so the diagonal is never set (matches 1-eye masking in the reference).
    if (v.x != v.y) { int i = v.x * SS + v.y; atomicOr(&s_bm[i >> 5], 1u << (i & 31)); }
    if (v.y != v.z) { int i = v.y * SS + v.z; atomicOr(&s_bm[i >> 5], 1u << (i & 31)); }
    if (v.z != v.w) { int i = v.z * SS + v.w; atomicOr(&s_bm[i >> 5], 1u << (i & 31)); }
    if (v.w != nxt) { int i = v.w * SS + nxt; atomicOr(&s_bm[i >> 5], 1u << (i & 31)); }
    if (v.x != d.x) { int i = v.x * SS + d.x; atomicOr(&s_bm[i >> 5], 1u << (i & 31)); }
    if (v.y != d.y) { int i = v.y * SS + d.y; atomicOr(&s_bm[i >> 5], 1u << (i & 31)); }
    if (v.z != d.z) { int i = v.z * SS + d.z; atomicOr(&s_bm[i >> 5], 1u << (i & 31)); }
    if (v.w != d.w) { int i = v.w * SS + d.w; atomicOr(&s_bm[i >> 5], 1u << (i & 31)); }

    // centers accumulation: 2 LDS atomics per pixel
    const ull yp = (1ULL << 40) | (ull)(uint)y;
    atomicAdd(&s_pk[v.x], yp); atomicAdd(&s_sx[v.x], (uint)x);
    atomicAdd(&s_pk[v.y], yp); atomicAdd(&s_sx[v.y], (uint)(x + 1));
    atomicAdd(&s_pk[v.z], yp); atomicAdd(&s_sx[v.z], (uint)(x + 2));
    atomicAdd(&s_pk[v.w], yp); atomicAdd(&s_sx[v.w], (uint)(x + 3));
  }
  __syncthreads();

  // flush adjacency bitmask (coalesced global atomicOr; ~2% of words are 0)
  for (int i = threadIdx.x; i < NWORDS; i += blockDim.x) {
    const uint val = s_bm[i];
    if (val) atomicOr(&wsOr[i], val);
  }
  // flush center partials (coalesced, transposed layout for the reduce kernel)
  for (int i = threadIdx.x; i < SS; i += blockDim.x) {
    const ull pk = s_pk[i];
    part[(0 * SS + i) * nb + blockIdx.x] = (uint)(pk >> 40);
    part[(1 * SS + i) * nb + blockIdx.x] = s_sx[i];
    part[(2 * SS + i) * nb + blockIdx.x] = (uint)(pk & ((1ULL << 40) - 1));
  }
}

// ---------------------------------------------------------------------------
// Expand bitmask -> float adjacency matrix. One thread per 4 cells (1 float4);
// 8 consecutive lanes share a word, consecutive float4 addresses -> coalesced.
// Fully writes all 512*512 cells (so no output memset needed).
// ---------------------------------------------------------------------------
__global__ __launch_bounds__(256) void adj_expand(
    const uint* __restrict__ wsOr, float* __restrict__ adj) {
  const int t = blockIdx.x * 256 + threadIdx.x;  // 65536 threads
  const uint bits = (wsOr[t >> 3] >> ((t & 7) * 4)) & 0xFu;
  float4 q;
  q.x = (bits & 1u) ? 1.0f : 0.0f;
  q.y = (bits & 2u) ? 1.0f : 0.0f;
  q.z = (bits & 4u) ? 1.0f : 0.0f;
  q.w = (bits & 8u) ? 1.0f : 0.0f;
  ((float4*)adj)[t] = q;
}

// ---------------------------------------------------------------------------
// One block (1 wave) per segment: coalesced partial reduction + divide.
// ---------------------------------------------------------------------------
__global__ __launch_bounds__(64) void seg_reduce(
    const uint* __restrict__ part, int nb, float* __restrict__ centers) {
  const int s = blockIdx.x;
  const int t = threadIdx.x;
  ull cnt = 0, sx = 0, sy = 0;
  for (int b = t; b < nb; b += 64) {
    cnt += part[(0 * SS + s) * nb + b];
    sx  += part[(1 * SS + s) * nb + b];
    sy  += part[(2 * SS + s) * nb + b];
  }
  for (int off = 32; off > 0; off >>= 1) {
    cnt += __shfl_down(cnt, off, 64);
    sx  += __shfl_down(sx,  off, 64);
    sy  += __shfl_down(sy,  off, 64);
  }
  if (t == 0) {
    const double dc = (double)cnt;
    centers[s * 2 + 0] = (float)((double)sx / dc);  // W-axis mean first (torch permute)
    centers[s * 2 + 1] = (float)((double)sy / dc);
  }
}

extern "C" void kernel_launch(void* const* d_in, const int* in_sizes, int n_in,
                              void* d_out, int out_size, void* d_ws, size_t ws_size,
                              hipStream_t stream) {
  const int* seg = (const int*)d_in[0];  // (1,1,2160,3840) int32
  float* out = (float*)d_out;
  float* adj = out;                       // 512*512
  float* centers = out + SS * SS;         // 512*2

  uint* wsOr = (uint*)d_ws;               // 8192 words = 32 KB
  uint* part = wsOr + NWORDS;             // 3*512*nb words

  int nb = 512;
  const size_t fixed = (size_t)NWORDS * sizeof(uint);
  const size_t per_block = (size_t)SS * 3 * sizeof(uint);  // 6 KB of partials per block
  if (ws_size < fixed + (size_t)nb * per_block) {
    nb = (int)((ws_size - fixed) / per_block);
    if (nb > 512) nb = 512;
    if (nb < 1) nb = 1;
  }

  hipMemsetAsync(wsOr, 0, fixed, stream);
  seg_main<<<nb, 512, 0, stream>>>(seg, wsOr, part, nb);
  adj_expand<<<SS * SS / 4 / 256, 256, 0, stream>>>(wsOr, adj);
  seg_reduce<<<SS, 64, 0, stream>>>(part, nb, centers);
}